// Round 2
// baseline (307.374 us; speedup 1.0000x reference)
//
#include <hip/hip_runtime.h>

// RelativeMultiHeadAttn: B=8 S=512 D_MODEL=1024 H=16 HD=64
// Round 1: fp16 pipeline (was bf16) for precision headroom.
//   ws layout (bytes):
//     xh  @ 0MiB   : x cast to fp16              [4096][1024]  (8 MiB)
//     wT  @ 8MiB   : Wqv transposed fp16         [2048][1024]  (4 MiB)
//     pos @ 12MiB  : sinusoid table fp16         [1088][64]    (136 KiB, rows>=1024 zero)
//     qrr @ 13MiB  : q + r_r_bias fp16           [B,H,S,64]    (8 MiB)
//     qrw @ 21MiB  : q + r_w_bias fp16           [B,H,S,64]    (8 MiB)
//     v   @ 29MiB  : v fp16                      [B,H,S,64]    (8 MiB)
//     vT  @ 37MiB  : v transposed fp16           [B,H,64,S]    (8 MiB)

using h8 = __attribute__((ext_vector_type(8))) _Float16;
using f32x4 = __attribute__((ext_vector_type(4))) float;

#define MFMA16(a, b, c) __builtin_amdgcn_mfma_f32_16x16x32_f16((a), (b), (c), 0, 0, 0)

// ---- cast x (fp32 -> fp16), 4,194,304 elems, 8/thread --------------------
__global__ __launch_bounds__(256) void k_cast_x(const float* __restrict__ x,
                                                _Float16* __restrict__ xh) {
  size_t idx = (size_t)blockIdx.x * 256 + threadIdx.x;
  const float* src = x + idx * 8;
  _Float16 tmp[8];
#pragma unroll
  for (int j = 0; j < 8; ++j) tmp[j] = (_Float16)src[j];
  *(h8*)(xh + idx * 8) = *(const h8*)tmp;
}

// ---- sinusoid table: pos[l][j], value index p = l-512 ---------------------
__global__ __launch_bounds__(256) void k_pos(_Float16* __restrict__ pos) {
  int idx = blockIdx.x * 256 + threadIdx.x;  // 1088*64 = 69632 exactly
  int l = idx >> 6, j = idx & 63;
  _Float16 r = (_Float16)0.f;
  if (l < 1024) {
    float p = (float)(l - 512);
    int jj = j & 31;
    float fr = expf((float)jj * (-9.210340371976184f / 31.0f));  // 10000^(-jj/31)
    float e = p * fr;
    r = (_Float16)((j < 32) ? sinf(e) : cosf(e));
  }
  pos[idx] = r;
}

// ---- transpose + cast Wqv [1024][2048] fp32 -> wT [2048][1024] fp16 ------
__global__ __launch_bounds__(256) void k_trans_w(const float* __restrict__ Wqv,
                                                 _Float16* __restrict__ wT) {
  __shared__ _Float16 t[64][72];
  int bk = blockIdx.x & 15, bn = blockIdx.x >> 4;  // 16 x 32 tiles of 64x64
  int k0 = bk * 64, n0 = bn * 64;
  int r = threadIdx.x >> 2, c = (threadIdx.x & 3) * 16;
  const float* src = Wqv + (size_t)(k0 + r) * 2048 + n0 + c;
#pragma unroll
  for (int j = 0; j < 16; ++j) t[r][c + j] = (_Float16)src[j];
  __syncthreads();
  _Float16 tmp[16];
#pragma unroll
  for (int j = 0; j < 16; ++j) tmp[j] = t[c + j][r];
  _Float16* dst = wT + (size_t)(n0 + r) * 1024 + k0 + c;
  *(h8*)dst = *(const h8*)tmp;
  *(h8*)(dst + 8) = *(const h8*)(tmp + 8);
}

// ---- GEMM qv = x @ Wqv; epilogue writes qrr/qrw (n<1024) and v ------------
__global__ __launch_bounds__(256) void k_gemm(const _Float16* __restrict__ xh,
                                              const _Float16* __restrict__ wT,
                                              const float* __restrict__ rr,
                                              const float* __restrict__ rw,
                                              _Float16* __restrict__ qrr,
                                              _Float16* __restrict__ qrw,
                                              _Float16* __restrict__ v) {
  int bid = blockIdx.x;
  int bm = bid & 63, bn = bid >> 6;  // 64 x 32 tiles of 64x64
  int w = threadIdx.x >> 6, lane = threadIdx.x & 63;
  int lr = lane & 15, lg = lane >> 4;
  int m0 = bm * 64 + (w >> 1) * 32;
  int n0 = bn * 64 + (w & 1) * 32;
  f32x4 acc[2][2] = {};
  const _Float16* pa0 = xh + (size_t)(m0 + lr) * 1024 + lg * 8;
  const _Float16* pa1 = pa0 + 16 * 1024;
  const _Float16* pb0 = wT + (size_t)(n0 + lr) * 1024 + lg * 8;
  const _Float16* pb1 = pb0 + 16 * 1024;
  for (int k0 = 0; k0 < 1024; k0 += 32) {
    h8 a0 = *(const h8*)(pa0 + k0);
    h8 a1 = *(const h8*)(pa1 + k0);
    h8 b0 = *(const h8*)(pb0 + k0);
    h8 b1 = *(const h8*)(pb1 + k0);
    acc[0][0] = MFMA16(a0, b0, acc[0][0]);
    acc[0][1] = MFMA16(a0, b1, acc[0][1]);
    acc[1][0] = MFMA16(a1, b0, acc[1][0]);
    acc[1][1] = MFMA16(a1, b1, acc[1][1]);
  }
#pragma unroll
  for (int mi = 0; mi < 2; ++mi)
#pragma unroll
    for (int ni = 0; ni < 2; ++ni)
#pragma unroll
      for (int r = 0; r < 4; ++r) {
        int m = m0 + mi * 16 + lg * 4 + r;
        int n = n0 + ni * 16 + lr;
        float val = acc[mi][ni][r];
        int b = m >> 9, s = m & 511;
        if (n < 1024) {
          int h = n >> 6, d = n & 63;
          size_t o = ((size_t)(b * 16 + h) * 512 + s) * 64 + d;
          qrr[o] = (_Float16)(val + rr[n]);
          qrw[o] = (_Float16)(val + rw[n]);
        } else {
          int n2 = n - 1024;
          int h = n2 >> 6, d = n2 & 63;
          v[((size_t)(b * 16 + h) * 512 + s) * 64 + d] = (_Float16)val;
        }
      }
}

// ---- transpose v [B,H,S,64] -> vT [B,H,64,S] ------------------------------
__global__ __launch_bounds__(256) void k_trans_v(const _Float16* __restrict__ v,
                                                 _Float16* __restrict__ vT) {
  __shared__ _Float16 t[64][72];
  int bid = blockIdx.x;  // 8 stile * 16 h * 8 b = 1024
  int st = bid & 7, h = (bid >> 3) & 15, b = bid >> 7;
  int r = threadIdx.x >> 2, c = (threadIdx.x & 3) * 16;
  const _Float16* src = v + ((size_t)(b * 16 + h) * 512 + st * 64 + r) * 64 + c;
  *(h8*)&t[r][c] = *(const h8*)src;
  *(h8*)&t[r][c + 8] = *(const h8*)(src + 8);
  __syncthreads();
  _Float16 tmp[16];
#pragma unroll
  for (int j = 0; j < 16; ++j) tmp[j] = t[c + j][r];
  _Float16* dst = vT + ((size_t)(b * 16 + h) * 64 + r) * 512 + st * 64 + c;
  *(h8*)dst = *(const h8*)tmp;
  *(h8*)(dst + 8) = *(const h8*)(tmp + 8);
}

// ---- attention: one block per (b, h, 64-row q-block) ----------------------
__global__ __launch_bounds__(256) void k_attn(const _Float16* __restrict__ xh,
                                              const _Float16* __restrict__ qrr,
                                              const _Float16* __restrict__ qrw,
                                              const _Float16* __restrict__ vT,
                                              const _Float16* __restrict__ pos,
                                              const int* __restrict__ mask,
                                              float* __restrict__ out) {
  __shared__ float Gs[64 * 128];       // BD diagonal-window GEMM output
  __shared__ _Float16 Ss[64 * 512];    // fp16 scores, then fp16 p (in place)
  __shared__ float rmax[64 * 4];
  __shared__ float rsum[64 * 4];

  int bid = blockIdx.x;
  int qb = bid & 7, h = (bid >> 3) & 15, b = bid >> 7;
  int q0 = qb * 64;
  int tid = threadIdx.x;
  int w = tid >> 6, lane = tid & 63;
  int lr = lane & 15, lg = lane >> 4;

  const size_t bh = (size_t)(b * 16 + h);
  const _Float16* qrr_p = qrr + (bh * 512 + q0 + 16 * w + lr) * 64 + lg * 8;
  const _Float16* qrw_p = qrw + (bh * 512 + q0 + 16 * w + lr) * 64 + lg * 8;
  const _Float16* kb = xh + (size_t)b * 512 * 1024 + h * 64;
  const _Float16* vTp = vT + bh * 64 * 512;
  const int* mrow = mask + b * 512;

  // A-fragments are the same for every k-tile: hoist.
  h8 aw0 = *(const h8*)(qrw_p);
  h8 aw1 = *(const h8*)(qrw_p + 32);
  h8 ar0 = *(const h8*)(qrr_p);
  h8 ar1 = *(const h8*)(qrr_p + 32);

  for (int t0 = 0; t0 < 512; t0 += 64) {
    int baseL = t0 - q0 + 449;  // min over (ii,tl) of l = t-i+512, minus local window
    // G[ii][w] = sum_d qrw[q0+ii][d] * pos[baseL+w][d]   (wave w -> rows 16w..16w+15)
#pragma unroll
    for (int wf = 0; wf < 8; ++wf) {
      const _Float16* pp = pos + (size_t)(baseL + wf * 16 + lr) * 64 + lg * 8;
      h8 b0 = *(const h8*)pp;
      h8 b1 = *(const h8*)(pp + 32);
      f32x4 c = {0.f, 0.f, 0.f, 0.f};
      c = MFMA16(aw0, b0, c);
      c = MFMA16(aw1, b1, c);
#pragma unroll
      for (int r = 0; r < 4; ++r)
        Gs[(16 * w + lg * 4 + r) * 128 + wf * 16 + lr] = c[r];
    }
    __syncthreads();
    // AC tile + fold in G, store fp16 scores
#pragma unroll
    for (int tf = 0; tf < 4; ++tf) {
      const _Float16* kp = kb + (size_t)(t0 + tf * 16 + lr) * 1024 + lg * 8;
      h8 b0 = *(const h8*)kp;
      h8 b1 = *(const h8*)(kp + 32);
      f32x4 c = {0.f, 0.f, 0.f, 0.f};
      c = MFMA16(ar0, b0, c);
      c = MFMA16(ar1, b1, c);
#pragma unroll
      for (int r = 0; r < 4; ++r) {
        int ii = 16 * w + lg * 4 + r;
        int tl = tf * 16 + lr;
        float s = c[r] + Gs[ii * 128 + tl + 63 - ii];  // BD[ii][t] = G[ii][tl+63-ii]
        Ss[ii * 512 + t0 + tl] = (_Float16)s;
      }
    }
    __syncthreads();
  }

  // ---- softmax: lane = row, wave w handles cols [128w, 128w+128) ----------
  {
    int row = lane;
    _Float16* srow = Ss + row * 512 + w * 128;
    float m = -3.4e38f;
    for (int c = 0; c < 16; ++c) {
      h8 ch = *(const h8*)(srow + c * 8);
#pragma unroll
      for (int j = 0; j < 8; ++j) {
        float s = (float)ch[j];
        s = mrow[w * 128 + c * 8 + j] ? s : -1e8f;
        m = fmaxf(m, s);
      }
    }
    rmax[row * 4 + w] = m;
    __syncthreads();
    m = fmaxf(fmaxf(rmax[row * 4 + 0], rmax[row * 4 + 1]),
              fmaxf(rmax[row * 4 + 2], rmax[row * 4 + 3]));
    float sum = 0.f;
    for (int c = 0; c < 16; ++c) {
      h8 ch = *(const h8*)(srow + c * 8);
      _Float16 ob[8];
#pragma unroll
      for (int j = 0; j < 8; ++j) {
        float s = (float)ch[j];
        s = mrow[w * 128 + c * 8 + j] ? s : -1e8f;
        float e = __expf(s - m);
        ob[j] = (_Float16)e;
        sum += (float)ob[j];  // accumulate the rounded value for consistency with PV
      }
      *(h8*)(srow + c * 8) = *(const h8*)ob;  // unnormalized p, fp16
    }
    rsum[row * 4 + w] = sum;
    __syncthreads();
  }

  // ---- PV: out[ii][d] = (p @ v) / rowsum ----------------------------------
#pragma unroll
  for (int df = 0; df < 4; ++df) {
    f32x4 acc = {0.f, 0.f, 0.f, 0.f};
    const _Float16* vp = vTp + (size_t)(df * 16 + lr) * 512 + lg * 8;
    const _Float16* pp = Ss + (16 * w + lr) * 512 + lg * 8;
#pragma unroll
    for (int kk = 0; kk < 16; ++kk) {
      h8 pa = *(const h8*)(pp + kk * 32);
      h8 vb = *(const h8*)(vp + kk * 32);
      acc = MFMA16(pa, vb, acc);
    }
#pragma unroll
    for (int r = 0; r < 4; ++r) {
      int ii = 16 * w + lg * 4 + r;
      float tot = rsum[ii * 4 + 0] + rsum[ii * 4 + 1] + rsum[ii * 4 + 2] + rsum[ii * 4 + 3];
      out[((size_t)b * 512 + q0 + ii) * 1024 + h * 64 + df * 16 + lr] = acc[r] / tot;
    }
  }
}

extern "C" void kernel_launch(void* const* d_in, const int* in_sizes, int n_in,
                              void* d_out, int out_size, void* d_ws, size_t ws_size,
                              hipStream_t stream) {
  const float* x = (const float*)d_in[0];
  const int* mask = (const int*)d_in[1];
  const float* Wqv = (const float*)d_in[2];
  const float* rr = (const float*)d_in[3];
  const float* rw = (const float*)d_in[4];
  float* out = (float*)d_out;
  char* ws = (char*)d_ws;
  const size_t MB = 1024 * 1024;
  _Float16* xh = (_Float16*)(ws);
  _Float16* wT = (_Float16*)(ws + 8 * MB);
  _Float16* pos = (_Float16*)(ws + 12 * MB);
  _Float16* qrr = (_Float16*)(ws + 13 * MB);
  _Float16* qrw = (_Float16*)(ws + 21 * MB);
  _Float16* v = (_Float16*)(ws + 29 * MB);
  _Float16* vT = (_Float16*)(ws + 37 * MB);

  k_cast_x<<<2048, 256, 0, stream>>>(x, xh);
  k_pos<<<272, 256, 0, stream>>>(pos);
  k_trans_w<<<512, 256, 0, stream>>>(Wqv, wT);
  k_gemm<<<2048, 256, 0, stream>>>(xh, wT, rr, rw, qrr, qrw, v);
  k_trans_v<<<1024, 256, 0, stream>>>(v, vT);
  k_attn<<<1024, 256, 0, stream>>>(xh, qrr, qrw, vT, pos, mask, out);
}

// Round 4
// 258.148 us; speedup vs baseline: 1.1907x; 1.1907x over previous
//
#include <hip/hip_runtime.h>

// RelativeMultiHeadAttn: B=8 S=512 D_MODEL=1024 H=16 HD=64
// Round 3: BD via rotation identity (no shift-gather):
//   BD[i][t] = qrw_i . pos[t-i+512] = rot(qrw_i, -i) . pos'[t],
//   pos'[t] = [sin(t f), cos(t f)] ; rot applied in k_gemm epilogue.
//   Scores = [qrr, qrw'] . [k, pos']^T  (single K=128 MFMA chain).
//   ws layout (bytes):
//     xh   @ 0MiB  : x cast to fp16             [4096][1024]  (8 MiB)
//     wT   @ 8MiB  : Wqv transposed fp16        [2048][1024]  (4 MiB)
//     posP @ 12MiB : [sin(t f), cos(t f)] fp16  [512][64]     (64 KiB)
//     qrr  @ 13MiB : q + r_r_bias fp16          [B,H,S,64]    (8 MiB)
//     qrwp @ 21MiB : rot(q + r_w_bias) fp16     [B,H,S,64]    (8 MiB)
//     v    @ 29MiB : v fp16                     [B,H,S,64]    (8 MiB)
//     vT   @ 37MiB : v transposed fp16          [B,H,64,S]    (8 MiB)

using h8 = __attribute__((ext_vector_type(8))) _Float16;
using f32x4 = __attribute__((ext_vector_type(4))) float;

#define MFMA16(a, b, c) __builtin_amdgcn_mfma_f32_16x16x32_f16((a), (b), (c), 0, 0, 0)

// ---- cast x (fp32 -> fp16), 4,194,304 elems, 8/thread --------------------
__global__ __launch_bounds__(256) void k_cast_x(const float* __restrict__ x,
                                                _Float16* __restrict__ xh) {
  size_t idx = (size_t)blockIdx.x * 256 + threadIdx.x;
  const float* src = x + idx * 8;
  _Float16 tmp[8];
#pragma unroll
  for (int j = 0; j < 8; ++j) tmp[j] = (_Float16)src[j];
  *(h8*)(xh + idx * 8) = *(const h8*)tmp;
}

// ---- pos' table: posP[t][j] = j<32 ? sin(t f_j) : cos(t f_{j-32}) ---------
__global__ __launch_bounds__(256) void k_posP(_Float16* __restrict__ posP) {
  int idx = blockIdx.x * 256 + threadIdx.x;  // 512*64 = 32768 exactly
  int t = idx >> 6, j = idx & 63;
  int jj = j & 31;
  float f = expf((float)jj * (-9.210340371976184f / 31.0f));  // 10000^(-jj/31)
  float ang = (float)t * f;
  posP[idx] = (_Float16)((j < 32) ? sinf(ang) : cosf(ang));
}

// ---- transpose + cast Wqv [1024][2048] fp32 -> wT [2048][1024] fp16 ------
__global__ __launch_bounds__(256) void k_trans_w(const float* __restrict__ Wqv,
                                                 _Float16* __restrict__ wT) {
  __shared__ _Float16 t[64][72];
  int bk = blockIdx.x & 15, bn = blockIdx.x >> 4;  // 16 x 32 tiles of 64x64
  int k0 = bk * 64, n0 = bn * 64;
  int r = threadIdx.x >> 2, c = (threadIdx.x & 3) * 16;
  const float* src = Wqv + (size_t)(k0 + r) * 2048 + n0 + c;
#pragma unroll
  for (int j = 0; j < 16; ++j) t[r][c + j] = (_Float16)src[j];
  __syncthreads();
  _Float16 tmp[16];
#pragma unroll
  for (int j = 0; j < 16; ++j) tmp[j] = t[c + j][r];
  _Float16* dst = wT + (size_t)(n0 + r) * 1024 + k0 + c;
  *(h8*)dst = *(const h8*)tmp;
  *(h8*)(dst + 8) = *(const h8*)(tmp + 8);
}

// ---- GEMM qv = x @ Wqv; epilogue writes qrr, rotated qrwp, v --------------
// wave w owns rows [bm*64 + 16w, +16), all 64 cols of the n-block
// (rotation pairs head-dims d and d+32 -> same lane: ni and ni+2).
__global__ __launch_bounds__(256) void k_gemm(const _Float16* __restrict__ xh,
                                              const _Float16* __restrict__ wT,
                                              const float* __restrict__ rr,
                                              const float* __restrict__ rw,
                                              _Float16* __restrict__ qrr,
                                              _Float16* __restrict__ qrwp,
                                              _Float16* __restrict__ v) {
  int bid = blockIdx.x;
  int bm = bid & 63, bn = bid >> 6;  // 64 x 32 tiles of 64x64
  int w = threadIdx.x >> 6, lane = threadIdx.x & 63;
  int lr = lane & 15, lg = lane >> 4;
  int m0 = bm * 64 + w * 16;
  int n0 = bn * 64;
  f32x4 acc[4] = {};
  const _Float16* pa = xh + (size_t)(m0 + lr) * 1024 + lg * 8;
  const _Float16* pb = wT + (size_t)(n0 + lr) * 1024 + lg * 8;
  for (int k0 = 0; k0 < 1024; k0 += 32) {
    h8 a = *(const h8*)(pa + k0);
    h8 b0 = *(const h8*)(pb + k0);
    h8 b1 = *(const h8*)(pb + 16 * 1024 + k0);
    h8 b2 = *(const h8*)(pb + 32 * 1024 + k0);
    h8 b3 = *(const h8*)(pb + 48 * 1024 + k0);
    acc[0] = MFMA16(a, b0, acc[0]);
    acc[1] = MFMA16(a, b1, acc[1]);
    acc[2] = MFMA16(a, b2, acc[2]);
    acc[3] = MFMA16(a, b3, acc[3]);
  }
  if (bn < 16) {
    int h = bn;
#pragma unroll
    for (int r = 0; r < 4; ++r) {
      int m = m0 + lg * 4 + r;
      int b = m >> 9, s = m & 511;
      size_t base = ((size_t)(b * 16 + h) * 512 + s) * 64;
#pragma unroll
      for (int ni = 0; ni < 4; ++ni) {
        int n = n0 + ni * 16 + lr;
        qrr[base + ni * 16 + lr] = (_Float16)(acc[ni][r] + rr[n]);
      }
#pragma unroll
      for (int ni = 0; ni < 2; ++ni) {
        int d = ni * 16 + lr;           // d in [0,32)
        int n = n0 + d;
        float qs = acc[ni][r] + rw[n];            // sin-half coeff
        float qc = acc[ni + 2][r] + rw[n + 32];   // cos-half coeff
        float f = expf((float)d * (-9.210340371976184f / 31.0f));
        float sn, cs;
        sincosf((float)s * f, &sn, &cs);
        // BD[i][t] = (qs*cos_i + qc*sin_i)*sin(t f) + (qc*cos_i - qs*sin_i)*cos(t f)
        qrwp[base + d] = (_Float16)(qs * cs + qc * sn);
        qrwp[base + d + 32] = (_Float16)(qc * cs - qs * sn);
      }
    }
  } else {
    int h = bn - 16;
#pragma unroll
    for (int r = 0; r < 4; ++r) {
      int m = m0 + lg * 4 + r;
      int b = m >> 9, s = m & 511;
      size_t base = ((size_t)(b * 16 + h) * 512 + s) * 64;
#pragma unroll
      for (int ni = 0; ni < 4; ++ni)
        v[base + ni * 16 + lr] = (_Float16)acc[ni][r];
    }
  }
}

// ---- transpose v [B,H,S,64] -> vT [B,H,64,S] ------------------------------
__global__ __launch_bounds__(256) void k_trans_v(const _Float16* __restrict__ v,
                                                 _Float16* __restrict__ vT) {
  __shared__ _Float16 t[64][72];
  int bid = blockIdx.x;  // 8 stile * 16 h * 8 b = 1024
  int st = bid & 7, h = (bid >> 3) & 15, b = bid >> 7;
  int r = threadIdx.x >> 2, c = (threadIdx.x & 3) * 16;
  const _Float16* src = v + ((size_t)(b * 16 + h) * 512 + st * 64 + r) * 64 + c;
  *(h8*)&t[r][c] = *(const h8*)src;
  *(h8*)&t[r][c + 8] = *(const h8*)(src + 8);
  __syncthreads();
  _Float16 tmp[16];
#pragma unroll
  for (int j = 0; j < 16; ++j) tmp[j] = t[c + j][r];
  _Float16* dst = vT + ((size_t)(b * 16 + h) * 64 + r) * 512 + st * 64 + c;
  *(h8*)dst = *(const h8*)tmp;
  *(h8*)(dst + 8) = *(const h8*)(tmp + 8);
}

// ---- flash attention: one block per (b, h, 64-row q-block) ----------------
// 4 waves, wave w owns q-rows [q0+16w, q0+16w+16).
// Scores: S[i][t] = qrr_i.k_t + qrwp_i.posP_t  (K=128, 4 MFMAs per frag).
__global__ __launch_bounds__(256) void k_attn(const _Float16* __restrict__ xh,
                                              const _Float16* __restrict__ qrr,
                                              const _Float16* __restrict__ qrwp,
                                              const _Float16* __restrict__ vT,
                                              const _Float16* __restrict__ posP,
                                              const int* __restrict__ mask,
                                              float* __restrict__ out) {
  __shared__ _Float16 Pl[4][16 * 72];  // per-wave P tile (stride 72 fp16)
  __shared__ float Ms[512];            // mask as float

  int bid = blockIdx.x;
  int qb = bid & 7, h = (bid >> 3) & 15, b = bid >> 7;
  int q0 = qb * 64;
  int tid = threadIdx.x;
  int w = tid >> 6, lane = tid & 63;
  int lr = lane & 15, lg = lane >> 4;

  const size_t bh = (size_t)(b * 16 + h);
  const _Float16* qrr_p = qrr + (bh * 512 + q0 + 16 * w + lr) * 64 + lg * 8;
  const _Float16* qrw_p = qrwp + (bh * 512 + q0 + 16 * w + lr) * 64 + lg * 8;
  const _Float16* kb = xh + (size_t)b * 512 * 1024 + h * 64;
  const _Float16* vTp = vT + bh * 64 * 512;
  const int* mrow = mask + b * 512;

  Ms[tid] = (float)mrow[tid];
  Ms[tid + 256] = (float)mrow[tid + 256];
  __syncthreads();

  // Hoist A-fragments (same for every k-tile).
  h8 ar0 = *(const h8*)(qrr_p);
  h8 ar1 = *(const h8*)(qrr_p + 32);
  h8 aw0 = *(const h8*)(qrw_p);
  h8 aw1 = *(const h8*)(qrw_p + 32);

  float m_run[4], l_run[4];
  f32x4 O[4];  // O[df][r]
#pragma unroll
  for (int r = 0; r < 4; ++r) { m_run[r] = -1e30f; l_run[r] = 0.f; }
#pragma unroll
  for (int df = 0; df < 4; ++df) O[df] = (f32x4){0.f, 0.f, 0.f, 0.f};

  _Float16* pw = &Pl[w][0];

  for (int t0 = 0; t0 < 512; t0 += 64) {
    // ---- scores s[tf][r] (row = lg*4+r, col = tf*16+lr), K=128 chain ------
    float s[4][4];
#pragma unroll
    for (int tf = 0; tf < 4; ++tf) {
      int t = t0 + tf * 16 + lr;
      const _Float16* kp = kb + (size_t)t * 1024 + lg * 8;
      const _Float16* pp = posP + (size_t)t * 64 + lg * 8;
      h8 k0 = *(const h8*)kp;
      h8 k1 = *(const h8*)(kp + 32);
      h8 p0 = *(const h8*)pp;
      h8 p1 = *(const h8*)(pp + 32);
      f32x4 c = {0.f, 0.f, 0.f, 0.f};
      c = MFMA16(ar0, k0, c);
      c = MFMA16(ar1, k1, c);
      c = MFMA16(aw0, p0, c);
      c = MFMA16(aw1, p1, c);
      float mm = Ms[t0 + tf * 16 + lr];
#pragma unroll
      for (int r = 0; r < 4; ++r) s[tf][r] = c[r] * mm - (1.f - mm) * 1e8f;
    }

    // ---- online softmax (reduce across the 16 lanes holding each row) -----
#pragma unroll
    for (int r = 0; r < 4; ++r) {
      float rm = fmaxf(fmaxf(s[0][r], s[1][r]), fmaxf(s[2][r], s[3][r]));
#pragma unroll
      for (int d = 1; d < 16; d <<= 1) rm = fmaxf(rm, __shfl_xor(rm, d));
      float mn = fmaxf(m_run[r], rm);
      float sc = __expf(m_run[r] - mn);
      m_run[r] = mn;
      float rs = 0.f;
#pragma unroll
      for (int tf = 0; tf < 4; ++tf) {
        float p = __expf(s[tf][r] - mn);
        _Float16 p16 = (_Float16)p;
        pw[(lg * 4 + r) * 72 + tf * 16 + lr] = p16;
        rs += (float)p16;  // accumulate rounded value for PV consistency
      }
#pragma unroll
      for (int d = 1; d < 16; d <<= 1) rs += __shfl_xor(rs, d);
      l_run[r] = l_run[r] * sc + rs;
#pragma unroll
      for (int df = 0; df < 4; ++df) O[df][r] *= sc;
    }
    __syncthreads();  // P tile fully written before PV reads

    // ---- PV: P as A-fragments from LDS, V^T from global as B --------------
    h8 pa0 = *(const h8*)(pw + lr * 72 + lg * 8);
    h8 pa1 = *(const h8*)(pw + lr * 72 + 32 + lg * 8);
#pragma unroll
    for (int df = 0; df < 4; ++df) {
      const _Float16* vp = vTp + (size_t)(df * 16 + lr) * 512 + t0 + lg * 8;
      h8 vb0 = *(const h8*)vp;
      h8 vb1 = *(const h8*)(vp + 32);
      O[df] = MFMA16(pa0, vb0, O[df]);
      O[df] = MFMA16(pa1, vb1, O[df]);
    }
    __syncthreads();  // PV reads done before next tile overwrites P
  }

  // ---- epilogue: normalize and store
#pragma unroll
  for (int df = 0; df < 4; ++df)
#pragma unroll
    for (int r = 0; r < 4; ++r) {
      int ii = 16 * w + lg * 4 + r;
      out[((size_t)b * 512 + q0 + ii) * 1024 + h * 64 + df * 16 + lr] = O[df][r] / l_run[r];
    }
}

extern "C" void kernel_launch(void* const* d_in, const int* in_sizes, int n_in,
                              void* d_out, int out_size, void* d_ws, size_t ws_size,
                              hipStream_t stream) {
  const float* x = (const float*)d_in[0];
  const int* mask = (const int*)d_in[1];
  const float* Wqv = (const float*)d_in[2];
  const float* rr = (const float*)d_in[3];
  const float* rw = (const float*)d_in[4];
  float* out = (float*)d_out;
  char* ws = (char*)d_ws;
  const size_t MB = 1024 * 1024;
  _Float16* xh = (_Float16*)(ws);
  _Float16* wT = (_Float16*)(ws + 8 * MB);
  _Float16* posP = (_Float16*)(ws + 12 * MB);
  _Float16* qrr = (_Float16*)(ws + 13 * MB);
  _Float16* qrwp = (_Float16*)(ws + 21 * MB);
  _Float16* v = (_Float16*)(ws + 29 * MB);
  _Float16* vT = (_Float16*)(ws + 37 * MB);

  k_cast_x<<<2048, 256, 0, stream>>>(x, xh);
  k_posP<<<128, 256, 0, stream>>>(posP);
  k_trans_w<<<512, 256, 0, stream>>>(Wqv, wT);
  k_gemm<<<2048, 256, 0, stream>>>(xh, wT, rr, rw, qrr, qrwp, v);
  k_trans_v<<<1024, 256, 0, stream>>>(v, vT);
  k_attn<<<1024, 256, 0, stream>>>(xh, qrr, qrwp, vT, posP, mask, out);
}

// Round 5
// 143.477 us; speedup vs baseline: 2.1423x; 1.7992x over previous
//
#include <hip/hip_runtime.h>

// RelativeMultiHeadAttn: B=8 S=512 D_MODEL=1024 H=16 HD=64
// Round 4: m97-style LDS-staged GEMM (128x128x32 tiles, global_load_lds).
//   BD via rotation identity (R3): BD[i][t] = rot(qrw_i,-i) . pos'[t].
//   ws layout (bytes):
//     xh   @ 0MiB  : x cast to fp16             [4096][1024]  (8 MiB)
//     wT   @ 8MiB  : Wqv transposed fp16        [2048][1024]  (4 MiB)
//     posP @ 12MiB : [sin(t f), cos(t f)] fp16  [512][64]     (64 KiB)
//     qrr  @ 13MiB : q + r_r_bias fp16          [B,H,S,64]    (8 MiB)
//     qrwp @ 21MiB : rot(q + r_w_bias) fp16     [B,H,S,64]    (8 MiB)
//     v    @ 29MiB : v fp16                     [B,H,S,64]    (8 MiB)
//     vT   @ 37MiB : v transposed fp16          [B,H,64,S]    (8 MiB)

using h8 = __attribute__((ext_vector_type(8))) _Float16;
using f32x4 = __attribute__((ext_vector_type(4))) float;

#define MFMA16(a, b, c) __builtin_amdgcn_mfma_f32_16x16x32_f16((a), (b), (c), 0, 0, 0)

#define GLOAD_LDS16(gp, lp)                                                        \
  __builtin_amdgcn_global_load_lds(                                                \
      (const __attribute__((address_space(1))) unsigned int*)(gp),                 \
      (__attribute__((address_space(3))) unsigned int*)(lp), 16, 0, 0)

// ---- cast x (fp32 -> fp16), 4,194,304 elems, 8/thread --------------------
__global__ __launch_bounds__(256) void k_cast_x(const float* __restrict__ x,
                                                _Float16* __restrict__ xh) {
  size_t idx = (size_t)blockIdx.x * 256 + threadIdx.x;
  const float* src = x + idx * 8;
  _Float16 tmp[8];
#pragma unroll
  for (int j = 0; j < 8; ++j) tmp[j] = (_Float16)src[j];
  *(h8*)(xh + idx * 8) = *(const h8*)tmp;
}

// ---- pos' table: posP[t][j] = j<32 ? sin(t f_j) : cos(t f_{j-32}) ---------
__global__ __launch_bounds__(256) void k_posP(_Float16* __restrict__ posP) {
  int idx = blockIdx.x * 256 + threadIdx.x;  // 512*64 = 32768 exactly
  int t = idx >> 6, j = idx & 63;
  int jj = j & 31;
  float f = expf((float)jj * (-9.210340371976184f / 31.0f));  // 10000^(-jj/31)
  float ang = (float)t * f;
  posP[idx] = (_Float16)((j < 32) ? sinf(ang) : cosf(ang));
}

// ---- transpose + cast Wqv [1024][2048] fp32 -> wT [2048][1024] fp16 ------
__global__ __launch_bounds__(256) void k_trans_w(const float* __restrict__ Wqv,
                                                 _Float16* __restrict__ wT) {
  __shared__ _Float16 t[64][72];
  int bk = blockIdx.x & 15, bn = blockIdx.x >> 4;  // 16 x 32 tiles of 64x64
  int k0 = bk * 64, n0 = bn * 64;
  int r = threadIdx.x >> 2, c = (threadIdx.x & 3) * 16;
  const float* src = Wqv + (size_t)(k0 + r) * 2048 + n0 + c;
#pragma unroll
  for (int j = 0; j < 16; ++j) t[r][c + j] = (_Float16)src[j];
  __syncthreads();
  _Float16 tmp[16];
#pragma unroll
  for (int j = 0; j < 16; ++j) tmp[j] = t[c + j][r];
  _Float16* dst = wT + (size_t)(n0 + r) * 1024 + k0 + c;
  *(h8*)dst = *(const h8*)tmp;
  *(h8*)(dst + 8) = *(const h8*)(tmp + 8);
}

// ---- GEMM qv = x @ Wqv, 128x128x32 LDS-staged (m97 structure) -------------
// grid 512: bm = bid&31 (M/128), bn = bid>>5 (N/128). 4 waves, wave (wm,wn)
// computes rows [bm*128+wm*64,+64) x cols [bn*128+wn*64,+64) = one head.
__global__ __launch_bounds__(256) void k_gemm(const _Float16* __restrict__ xh,
                                              const _Float16* __restrict__ wT,
                                              const float* __restrict__ rr,
                                              const float* __restrict__ rw,
                                              _Float16* __restrict__ qrr,
                                              _Float16* __restrict__ qrwp,
                                              _Float16* __restrict__ v) {
  __shared__ _Float16 At[128 * 32];
  __shared__ _Float16 Bt[128 * 32];

  int bid = blockIdx.x;
  int bm = bid & 31, bn = bid >> 5;
  int tid = threadIdx.x;
  int w = tid >> 6, lane = tid & 63;
  int lr = lane & 15, lg = lane >> 4;

  // staging source: wave w stages A rows [32w,32w+32) and B rows [32w,32w+32)
  // lane -> row = lane>>2, col8 = (lane&3)*8 ; LDS linear matches lane*16B.
  const _Float16* gA = xh + (size_t)(bm * 128 + 32 * w + (lane >> 2)) * 1024 + (lane & 3) * 8;
  const _Float16* gB = wT + (size_t)(bn * 128 + 32 * w + (lane >> 2)) * 1024 + (lane & 3) * 8;
  _Float16* lA0 = &At[(32 * w) * 32];
  _Float16* lA1 = &At[(32 * w + 16) * 32];
  _Float16* lB0 = &Bt[(32 * w) * 32];
  _Float16* lB1 = &Bt[(32 * w + 16) * 32];

  int wm = w >> 1, wn = w & 1;
  const _Float16* la = &At[(wm * 64 + lr) * 32 + lg * 8];
  const _Float16* lb = &Bt[(wn * 64 + lr) * 32 + lg * 8];

  f32x4 acc[4][4] = {};

  for (int k0 = 0; k0 < 1024; k0 += 32) {
    GLOAD_LDS16(gA + k0, lA0);
    GLOAD_LDS16(gA + 16 * 1024 + k0, lA1);
    GLOAD_LDS16(gB + k0, lB0);
    GLOAD_LDS16(gB + 16 * 1024 + k0, lB1);
    __syncthreads();  // drains vmcnt -> tiles ready
    h8 af[4], bf[4];
#pragma unroll
    for (int mi = 0; mi < 4; ++mi) af[mi] = *(const h8*)(la + mi * 512);
#pragma unroll
    for (int ni = 0; ni < 4; ++ni) bf[ni] = *(const h8*)(lb + ni * 512);
#pragma unroll
    for (int mi = 0; mi < 4; ++mi)
#pragma unroll
      for (int ni = 0; ni < 4; ++ni)
        acc[mi][ni] = MFMA16(af[mi], bf[ni], acc[mi][ni]);
    __syncthreads();  // frag reads done before next-tile staging
  }

  // ---- epilogue ----------------------------------------------------------
  int hg = bn * 2 + wn;       // global 64-col group = head index (0..31)
  int mb = bm * 128 + wm * 64;
  if (hg < 16) {
    int h = hg;
    float rrv[4], rwv[4];
#pragma unroll
    for (int ni = 0; ni < 4; ++ni) {
      rrv[ni] = rr[h * 64 + ni * 16 + lr];
      rwv[ni] = rw[h * 64 + ni * 16 + lr];
    }
    float f0 = expf((float)lr * (-9.210340371976184f / 31.0f));
    float f1 = expf((float)(16 + lr) * (-9.210340371976184f / 31.0f));
#pragma unroll
    for (int mi = 0; mi < 4; ++mi)
#pragma unroll
      for (int r = 0; r < 4; ++r) {
        int m = mb + mi * 16 + lg * 4 + r;
        int b = m >> 9, s = m & 511;
        size_t base = ((size_t)(b * 16 + h) * 512 + s) * 64;
#pragma unroll
        for (int ni = 0; ni < 4; ++ni)
          qrr[base + ni * 16 + lr] = (_Float16)(acc[mi][ni][r] + rrv[ni]);
        {
          float qs = acc[mi][0][r] + rwv[0], qc = acc[mi][2][r] + rwv[2];
          float sn, cs;
          sincosf((float)s * f0, &sn, &cs);
          qrwp[base + lr] = (_Float16)(qs * cs + qc * sn);
          qrwp[base + lr + 32] = (_Float16)(qc * cs - qs * sn);
        }
        {
          float qs = acc[mi][1][r] + rwv[1], qc = acc[mi][3][r] + rwv[3];
          float sn, cs;
          sincosf((float)s * f1, &sn, &cs);
          qrwp[base + 16 + lr] = (_Float16)(qs * cs + qc * sn);
          qrwp[base + 16 + lr + 32] = (_Float16)(qc * cs - qs * sn);
        }
      }
  } else {
    int h = hg - 16;
#pragma unroll
    for (int mi = 0; mi < 4; ++mi)
#pragma unroll
      for (int r = 0; r < 4; ++r) {
        int m = mb + mi * 16 + lg * 4 + r;
        int b = m >> 9, s = m & 511;
        size_t base = ((size_t)(b * 16 + h) * 512 + s) * 64;
#pragma unroll
        for (int ni = 0; ni < 4; ++ni)
          v[base + ni * 16 + lr] = (_Float16)acc[mi][ni][r];
      }
  }
}

// ---- transpose v [B,H,S,64] -> vT [B,H,64,S] ------------------------------
__global__ __launch_bounds__(256) void k_trans_v(const _Float16* __restrict__ v,
                                                 _Float16* __restrict__ vT) {
  __shared__ _Float16 t[64][72];
  int bid = blockIdx.x;  // 8 stile * 16 h * 8 b = 1024
  int st = bid & 7, h = (bid >> 3) & 15, b = bid >> 7;
  int r = threadIdx.x >> 2, c = (threadIdx.x & 3) * 16;
  const _Float16* src = v + ((size_t)(b * 16 + h) * 512 + st * 64 + r) * 64 + c;
  *(h8*)&t[r][c] = *(const h8*)src;
  *(h8*)&t[r][c + 8] = *(const h8*)(src + 8);
  __syncthreads();
  _Float16 tmp[16];
#pragma unroll
  for (int j = 0; j < 16; ++j) tmp[j] = t[c + j][r];
  _Float16* dst = vT + ((size_t)(b * 16 + h) * 64 + r) * 512 + st * 64 + c;
  *(h8*)dst = *(const h8*)tmp;
  *(h8*)(dst + 8) = *(const h8*)(tmp + 8);
}

// ---- flash attention: one block per (b, h, 64-row q-block) ----------------
__global__ __launch_bounds__(256) void k_attn(const _Float16* __restrict__ xh,
                                              const _Float16* __restrict__ qrr,
                                              const _Float16* __restrict__ qrwp,
                                              const _Float16* __restrict__ vT,
                                              const _Float16* __restrict__ posP,
                                              const int* __restrict__ mask,
                                              float* __restrict__ out) {
  __shared__ _Float16 Pl[4][16 * 72];  // per-wave P tile (stride 72 fp16)
  __shared__ float Ms[512];            // mask as float

  int bid = blockIdx.x;
  int qb = bid & 7, h = (bid >> 3) & 15, b = bid >> 7;
  int q0 = qb * 64;
  int tid = threadIdx.x;
  int w = tid >> 6, lane = tid & 63;
  int lr = lane & 15, lg = lane >> 4;

  const size_t bh = (size_t)(b * 16 + h);
  const _Float16* qrr_p = qrr + (bh * 512 + q0 + 16 * w + lr) * 64 + lg * 8;
  const _Float16* qrw_p = qrwp + (bh * 512 + q0 + 16 * w + lr) * 64 + lg * 8;
  const _Float16* kb = xh + (size_t)b * 512 * 1024 + h * 64;
  const _Float16* vTp = vT + bh * 64 * 512;
  const int* mrow = mask + b * 512;

  Ms[tid] = (float)mrow[tid];
  Ms[tid + 256] = (float)mrow[tid + 256];
  __syncthreads();

  // Hoist A-fragments (same for every k-tile).
  h8 ar0 = *(const h8*)(qrr_p);
  h8 ar1 = *(const h8*)(qrr_p + 32);
  h8 aw0 = *(const h8*)(qrw_p);
  h8 aw1 = *(const h8*)(qrw_p + 32);

  float m_run[4], l_run[4];
  f32x4 O[4];  // O[df][r]
#pragma unroll
  for (int r = 0; r < 4; ++r) { m_run[r] = -1e30f; l_run[r] = 0.f; }
#pragma unroll
  for (int df = 0; df < 4; ++df) O[df] = (f32x4){0.f, 0.f, 0.f, 0.f};

  _Float16* pw = &Pl[w][0];

  for (int t0 = 0; t0 < 512; t0 += 64) {
    // ---- scores s[tf][r] (row = lg*4+r, col = tf*16+lr), K=128 chain ------
    float s[4][4];
#pragma unroll
    for (int tf = 0; tf < 4; ++tf) {
      int t = t0 + tf * 16 + lr;
      const _Float16* kp = kb + (size_t)t * 1024 + lg * 8;
      const _Float16* pp = posP + (size_t)t * 64 + lg * 8;
      h8 k0 = *(const h8*)kp;
      h8 k1 = *(const h8*)(kp + 32);
      h8 p0 = *(const h8*)pp;
      h8 p1 = *(const h8*)(pp + 32);
      f32x4 c = {0.f, 0.f, 0.f, 0.f};
      c = MFMA16(ar0, k0, c);
      c = MFMA16(ar1, k1, c);
      c = MFMA16(aw0, p0, c);
      c = MFMA16(aw1, p1, c);
      float mm = Ms[t0 + tf * 16 + lr];
#pragma unroll
      for (int r = 0; r < 4; ++r) s[tf][r] = c[r] * mm - (1.f - mm) * 1e8f;
    }

    // ---- online softmax (reduce across the 16 lanes holding each row) -----
#pragma unroll
    for (int r = 0; r < 4; ++r) {
      float rm = fmaxf(fmaxf(s[0][r], s[1][r]), fmaxf(s[2][r], s[3][r]));
#pragma unroll
      for (int d = 1; d < 16; d <<= 1) rm = fmaxf(rm, __shfl_xor(rm, d));
      float mn = fmaxf(m_run[r], rm);
      float sc = __expf(m_run[r] - mn);
      m_run[r] = mn;
      float rs = 0.f;
#pragma unroll
      for (int tf = 0; tf < 4; ++tf) {
        float p = __expf(s[tf][r] - mn);
        _Float16 p16 = (_Float16)p;
        pw[(lg * 4 + r) * 72 + tf * 16 + lr] = p16;
        rs += (float)p16;  // accumulate rounded value for PV consistency
      }
#pragma unroll
      for (int d = 1; d < 16; d <<= 1) rs += __shfl_xor(rs, d);
      l_run[r] = l_run[r] * sc + rs;
#pragma unroll
      for (int df = 0; df < 4; ++df) O[df][r] *= sc;
    }
    __syncthreads();  // P tile fully written before PV reads

    // ---- PV: P as A-fragments from LDS, V^T from global as B --------------
    h8 pa0 = *(const h8*)(pw + lr * 72 + lg * 8);
    h8 pa1 = *(const h8*)(pw + lr * 72 + 32 + lg * 8);
#pragma unroll
    for (int df = 0; df < 4; ++df) {
      const _Float16* vp = vTp + (size_t)(df * 16 + lr) * 512 + t0 + lg * 8;
      h8 vb0 = *(const h8*)vp;
      h8 vb1 = *(const h8*)(vp + 32);
      O[df] = MFMA16(pa0, vb0, O[df]);
      O[df] = MFMA16(pa1, vb1, O[df]);
    }
    __syncthreads();  // PV reads done before next tile overwrites P
  }

  // ---- epilogue: normalize and store
#pragma unroll
  for (int df = 0; df < 4; ++df)
#pragma unroll
    for (int r = 0; r < 4; ++r) {
      int ii = 16 * w + lg * 4 + r;
      out[((size_t)b * 512 + q0 + ii) * 1024 + h * 64 + df * 16 + lr] = O[df][r] / l_run[r];
    }
}

extern "C" void kernel_launch(void* const* d_in, const int* in_sizes, int n_in,
                              void* d_out, int out_size, void* d_ws, size_t ws_size,
                              hipStream_t stream) {
  const float* x = (const float*)d_in[0];
  const int* mask = (const int*)d_in[1];
  const float* Wqv = (const float*)d_in[2];
  const float* rr = (const float*)d_in[3];
  const float* rw = (const float*)d_in[4];
  float* out = (float*)d_out;
  char* ws = (char*)d_ws;
  const size_t MB = 1024 * 1024;
  _Float16* xh = (_Float16*)(ws);
  _Float16* wT = (_Float16*)(ws + 8 * MB);
  _Float16* posP = (_Float16*)(ws + 12 * MB);
  _Float16* qrr = (_Float16*)(ws + 13 * MB);
  _Float16* qrwp = (_Float16*)(ws + 21 * MB);
  _Float16* v = (_Float16*)(ws + 29 * MB);
  _Float16* vT = (_Float16*)(ws + 37 * MB);

  k_cast_x<<<2048, 256, 0, stream>>>(x, xh);
  k_posP<<<128, 256, 0, stream>>>(posP);
  k_trans_w<<<512, 256, 0, stream>>>(Wqv, wT);
  k_gemm<<<512, 256, 0, stream>>>(xh, wT, rr, rw, qrr, qrwp, v);
  k_trans_v<<<1024, 256, 0, stream>>>(v, vT);
  k_attn<<<1024, 256, 0, stream>>>(xh, qrr, qrwp, vT, posP, mask, out);
}

// Round 6
// 139.876 us; speedup vs baseline: 2.1975x; 1.0257x over previous
//
#include <hip/hip_runtime.h>

// RelativeMultiHeadAttn: B=8 S=512 D_MODEL=1024 H=16 HD=64
// Round 5: k_attn 128-wide KV tiles + XCD-locality block decode.
//   BD via rotation identity (R3): BD[i][t] = rot(qrw_i,-i) . pos'[t].
//   ws layout (bytes):
//     xh   @ 0MiB  : x cast to fp16             [4096][1024]  (8 MiB)
//     wT   @ 8MiB  : Wqv transposed fp16        [2048][1024]  (4 MiB)
//     posP @ 12MiB : [sin(t f), cos(t f)] fp16  [512][64]     (64 KiB)
//     qrr  @ 13MiB : q + r_r_bias fp16          [B,H,S,64]    (8 MiB)
//     qrwp @ 21MiB : rot(q + r_w_bias) fp16     [B,H,S,64]    (8 MiB)
//     v    @ 29MiB : v fp16                     [B,H,S,64]    (8 MiB)
//     vT   @ 37MiB : v transposed fp16          [B,H,64,S]    (8 MiB)

using h8 = __attribute__((ext_vector_type(8))) _Float16;
using f32x4 = __attribute__((ext_vector_type(4))) float;

#define MFMA16(a, b, c) __builtin_amdgcn_mfma_f32_16x16x32_f16((a), (b), (c), 0, 0, 0)

#define GLOAD_LDS16(gp, lp)                                                        \
  __builtin_amdgcn_global_load_lds(                                                \
      (const __attribute__((address_space(1))) unsigned int*)(gp),                 \
      (__attribute__((address_space(3))) unsigned int*)(lp), 16, 0, 0)

// ---- cast x (fp32 -> fp16), 4,194,304 elems, 8/thread --------------------
__global__ __launch_bounds__(256) void k_cast_x(const float* __restrict__ x,
                                                _Float16* __restrict__ xh) {
  size_t idx = (size_t)blockIdx.x * 256 + threadIdx.x;
  const float* src = x + idx * 8;
  _Float16 tmp[8];
#pragma unroll
  for (int j = 0; j < 8; ++j) tmp[j] = (_Float16)src[j];
  *(h8*)(xh + idx * 8) = *(const h8*)tmp;
}

// ---- pos' table: posP[t][j] = j<32 ? sin(t f_j) : cos(t f_{j-32}) ---------
__global__ __launch_bounds__(256) void k_posP(_Float16* __restrict__ posP) {
  int idx = blockIdx.x * 256 + threadIdx.x;  // 512*64 = 32768 exactly
  int t = idx >> 6, j = idx & 63;
  int jj = j & 31;
  float f = expf((float)jj * (-9.210340371976184f / 31.0f));  // 10000^(-jj/31)
  float ang = (float)t * f;
  posP[idx] = (_Float16)((j < 32) ? sinf(ang) : cosf(ang));
}

// ---- transpose + cast Wqv [1024][2048] fp32 -> wT [2048][1024] fp16 ------
__global__ __launch_bounds__(256) void k_trans_w(const float* __restrict__ Wqv,
                                                 _Float16* __restrict__ wT) {
  __shared__ _Float16 t[64][72];
  int bk = blockIdx.x & 15, bn = blockIdx.x >> 4;  // 16 x 32 tiles of 64x64
  int k0 = bk * 64, n0 = bn * 64;
  int r = threadIdx.x >> 2, c = (threadIdx.x & 3) * 16;
  const float* src = Wqv + (size_t)(k0 + r) * 2048 + n0 + c;
#pragma unroll
  for (int j = 0; j < 16; ++j) t[r][c + j] = (_Float16)src[j];
  __syncthreads();
  _Float16 tmp[16];
#pragma unroll
  for (int j = 0; j < 16; ++j) tmp[j] = t[c + j][r];
  _Float16* dst = wT + (size_t)(n0 + r) * 1024 + k0 + c;
  *(h8*)dst = *(const h8*)tmp;
  *(h8*)(dst + 8) = *(const h8*)(tmp + 8);
}

// ---- GEMM qv = x @ Wqv, 128x128x32 LDS-staged (m97 structure) -------------
__global__ __launch_bounds__(256) void k_gemm(const _Float16* __restrict__ xh,
                                              const _Float16* __restrict__ wT,
                                              const float* __restrict__ rr,
                                              const float* __restrict__ rw,
                                              _Float16* __restrict__ qrr,
                                              _Float16* __restrict__ qrwp,
                                              _Float16* __restrict__ v) {
  __shared__ _Float16 At[128 * 32];
  __shared__ _Float16 Bt[128 * 32];

  int bid = blockIdx.x;
  int bm = bid & 31, bn = bid >> 5;
  int tid = threadIdx.x;
  int w = tid >> 6, lane = tid & 63;
  int lr = lane & 15, lg = lane >> 4;

  const _Float16* gA = xh + (size_t)(bm * 128 + 32 * w + (lane >> 2)) * 1024 + (lane & 3) * 8;
  const _Float16* gB = wT + (size_t)(bn * 128 + 32 * w + (lane >> 2)) * 1024 + (lane & 3) * 8;
  _Float16* lA0 = &At[(32 * w) * 32];
  _Float16* lA1 = &At[(32 * w + 16) * 32];
  _Float16* lB0 = &Bt[(32 * w) * 32];
  _Float16* lB1 = &Bt[(32 * w + 16) * 32];

  int wm = w >> 1, wn = w & 1;
  const _Float16* la = &At[(wm * 64 + lr) * 32 + lg * 8];
  const _Float16* lb = &Bt[(wn * 64 + lr) * 32 + lg * 8];

  f32x4 acc[4][4] = {};

  for (int k0 = 0; k0 < 1024; k0 += 32) {
    GLOAD_LDS16(gA + k0, lA0);
    GLOAD_LDS16(gA + 16 * 1024 + k0, lA1);
    GLOAD_LDS16(gB + k0, lB0);
    GLOAD_LDS16(gB + 16 * 1024 + k0, lB1);
    __syncthreads();
    h8 af[4], bf[4];
#pragma unroll
    for (int mi = 0; mi < 4; ++mi) af[mi] = *(const h8*)(la + mi * 512);
#pragma unroll
    for (int ni = 0; ni < 4; ++ni) bf[ni] = *(const h8*)(lb + ni * 512);
#pragma unroll
    for (int mi = 0; mi < 4; ++mi)
#pragma unroll
      for (int ni = 0; ni < 4; ++ni)
        acc[mi][ni] = MFMA16(af[mi], bf[ni], acc[mi][ni]);
    __syncthreads();
  }

  int hg = bn * 2 + wn;
  int mb = bm * 128 + wm * 64;
  if (hg < 16) {
    int h = hg;
    float rrv[4], rwv[4];
#pragma unroll
    for (int ni = 0; ni < 4; ++ni) {
      rrv[ni] = rr[h * 64 + ni * 16 + lr];
      rwv[ni] = rw[h * 64 + ni * 16 + lr];
    }
    float f0 = expf((float)lr * (-9.210340371976184f / 31.0f));
    float f1 = expf((float)(16 + lr) * (-9.210340371976184f / 31.0f));
#pragma unroll
    for (int mi = 0; mi < 4; ++mi)
#pragma unroll
      for (int r = 0; r < 4; ++r) {
        int m = mb + mi * 16 + lg * 4 + r;
        int b = m >> 9, s = m & 511;
        size_t base = ((size_t)(b * 16 + h) * 512 + s) * 64;
#pragma unroll
        for (int ni = 0; ni < 4; ++ni)
          qrr[base + ni * 16 + lr] = (_Float16)(acc[mi][ni][r] + rrv[ni]);
        {
          float qs = acc[mi][0][r] + rwv[0], qc = acc[mi][2][r] + rwv[2];
          float sn, cs;
          sincosf((float)s * f0, &sn, &cs);
          qrwp[base + lr] = (_Float16)(qs * cs + qc * sn);
          qrwp[base + lr + 32] = (_Float16)(qc * cs - qs * sn);
        }
        {
          float qs = acc[mi][1][r] + rwv[1], qc = acc[mi][3][r] + rwv[3];
          float sn, cs;
          sincosf((float)s * f1, &sn, &cs);
          qrwp[base + 16 + lr] = (_Float16)(qs * cs + qc * sn);
          qrwp[base + 16 + lr + 32] = (_Float16)(qc * cs - qs * sn);
        }
      }
  } else {
    int h = hg - 16;
#pragma unroll
    for (int mi = 0; mi < 4; ++mi)
#pragma unroll
      for (int r = 0; r < 4; ++r) {
        int m = mb + mi * 16 + lg * 4 + r;
        int b = m >> 9, s = m & 511;
        size_t base = ((size_t)(b * 16 + h) * 512 + s) * 64;
#pragma unroll
        for (int ni = 0; ni < 4; ++ni)
          v[base + ni * 16 + lr] = (_Float16)acc[mi][ni][r];
      }
  }
}

// ---- transpose v [B,H,S,64] -> vT [B,H,64,S] ------------------------------
__global__ __launch_bounds__(256) void k_trans_v(const _Float16* __restrict__ v,
                                                 _Float16* __restrict__ vT) {
  __shared__ _Float16 t[64][72];
  int bid = blockIdx.x;  // 8 stile * 16 h * 8 b = 1024
  int st = bid & 7, h = (bid >> 3) & 15, b = bid >> 7;
  int r = threadIdx.x >> 2, c = (threadIdx.x & 3) * 16;
  const _Float16* src = v + ((size_t)(b * 16 + h) * 512 + st * 64 + r) * 64 + c;
  *(h8*)&t[r][c] = *(const h8*)src;
  *(h8*)&t[r][c + 8] = *(const h8*)(src + 8);
  __syncthreads();
  _Float16 tmp[16];
#pragma unroll
  for (int j = 0; j < 16; ++j) tmp[j] = t[c + j][r];
  _Float16* dst = vT + ((size_t)(b * 16 + h) * 64 + r) * 512 + st * 64 + c;
  *(h8*)dst = *(const h8*)tmp;
  *(h8*)(dst + 8) = *(const h8*)(tmp + 8);
}

// ---- flash attention: one block per (b, h, 64-row q-block) ----------------
// Decode: qb = bid>>7, bh = bid&127  ->  all 8 q-blocks of one (b,h) share
// bid mod 8 (= XCD under round-robin) -> K/V stay in one XCD's L2.
// 128-wide KV tiles: 4 iterations, loads issued at tile top for ILP.
__global__ __launch_bounds__(256, 4) void k_attn(const _Float16* __restrict__ xh,
                                                 const _Float16* __restrict__ qrr,
                                                 const _Float16* __restrict__ qrwp,
                                                 const _Float16* __restrict__ vT,
                                                 const _Float16* __restrict__ posP,
                                                 const int* __restrict__ mask,
                                                 float* __restrict__ out) {
  __shared__ _Float16 Pl[4][16 * 136];  // per-wave P tile (stride 136 fp16, 16B-aligned)
  __shared__ float Ms[512];             // mask as float

  int bid = blockIdx.x;
  int qb = bid >> 7, h = bid & 15, b = (bid >> 4) & 7;
  int q0 = qb * 64;
  int tid = threadIdx.x;
  int w = tid >> 6, lane = tid & 63;
  int lr = lane & 15, lg = lane >> 4;

  const size_t bh = (size_t)(b * 16 + h);
  const _Float16* qrr_p = qrr + (bh * 512 + q0 + 16 * w + lr) * 64 + lg * 8;
  const _Float16* qrw_p = qrwp + (bh * 512 + q0 + 16 * w + lr) * 64 + lg * 8;
  const _Float16* kb = xh + (size_t)b * 512 * 1024 + h * 64;
  const _Float16* vTp = vT + bh * 64 * 512;
  const int* mrow = mask + b * 512;

  Ms[tid] = (float)mrow[tid];
  Ms[tid + 256] = (float)mrow[tid + 256];
  __syncthreads();

  // Hoist A-fragments (same for every k-tile).
  h8 ar0 = *(const h8*)(qrr_p);
  h8 ar1 = *(const h8*)(qrr_p + 32);
  h8 aw0 = *(const h8*)(qrw_p);
  h8 aw1 = *(const h8*)(qrw_p + 32);

  float m_run[4], l_run[4];
  f32x4 O[4];  // O[df][r]
#pragma unroll
  for (int r = 0; r < 4; ++r) { m_run[r] = -1e30f; l_run[r] = 0.f; }
#pragma unroll
  for (int df = 0; df < 4; ++df) O[df] = (f32x4){0.f, 0.f, 0.f, 0.f};

  _Float16* pw = &Pl[w][0];

  for (int t0 = 0; t0 < 512; t0 += 128) {
    // ---- scores s[tf][r] (row = lg*4+r, col = tf*16+lr), 8 col-frags ------
    float s[8][4];
#pragma unroll
    for (int tf = 0; tf < 8; ++tf) {
      int t = t0 + tf * 16 + lr;
      const _Float16* kp = kb + (size_t)t * 1024 + lg * 8;
      const _Float16* pp = posP + (size_t)t * 64 + lg * 8;
      h8 k0 = *(const h8*)kp;
      h8 k1 = *(const h8*)(kp + 32);
      h8 p0 = *(const h8*)pp;
      h8 p1 = *(const h8*)(pp + 32);
      f32x4 c = {0.f, 0.f, 0.f, 0.f};
      c = MFMA16(ar0, k0, c);
      c = MFMA16(ar1, k1, c);
      c = MFMA16(aw0, p0, c);
      c = MFMA16(aw1, p1, c);
      float mm = Ms[t0 + tf * 16 + lr];
#pragma unroll
      for (int r = 0; r < 4; ++r) s[tf][r] = c[r] * mm - (1.f - mm) * 1e8f;
    }

    // ---- online softmax (reduce across the 16 lanes holding each row) -----
#pragma unroll
    for (int r = 0; r < 4; ++r) {
      float rm = s[0][r];
#pragma unroll
      for (int tf = 1; tf < 8; ++tf) rm = fmaxf(rm, s[tf][r]);
#pragma unroll
      for (int d = 1; d < 16; d <<= 1) rm = fmaxf(rm, __shfl_xor(rm, d));
      float mn = fmaxf(m_run[r], rm);
      float sc = __expf(m_run[r] - mn);
      m_run[r] = mn;
      float rs = 0.f;
#pragma unroll
      for (int tf = 0; tf < 8; ++tf) {
        float p = __expf(s[tf][r] - mn);
        _Float16 p16 = (_Float16)p;
        pw[(lg * 4 + r) * 136 + tf * 16 + lr] = p16;
        rs += (float)p16;  // accumulate rounded value for PV consistency
      }
#pragma unroll
      for (int d = 1; d < 16; d <<= 1) rs += __shfl_xor(rs, d);
      l_run[r] = l_run[r] * sc + rs;
#pragma unroll
      for (int df = 0; df < 4; ++df) O[df][r] *= sc;
    }
    __syncthreads();  // P tile fully written before PV reads

    // ---- PV: P as A-fragments from LDS (K=128), V^T from global as B ------
    h8 pa[4];
#pragma unroll
    for (int ks = 0; ks < 4; ++ks)
      pa[ks] = *(const h8*)(pw + lr * 136 + ks * 32 + lg * 8);
#pragma unroll
    for (int df = 0; df < 4; ++df) {
      const _Float16* vp = vTp + (size_t)(df * 16 + lr) * 512 + t0 + lg * 8;
#pragma unroll
      for (int ks = 0; ks < 4; ++ks) {
        h8 vb = *(const h8*)(vp + ks * 32);
        O[df] = MFMA16(pa[ks], vb, O[df]);
      }
    }
    __syncthreads();  // PV reads done before next tile overwrites P
  }

  // ---- epilogue: normalize and store
#pragma unroll
  for (int df = 0; df < 4; ++df)
#pragma unroll
    for (int r = 0; r < 4; ++r) {
      int ii = 16 * w + lg * 4 + r;
      out[((size_t)b * 512 + q0 + ii) * 1024 + h * 64 + df * 16 + lr] = O[df][r] / l_run[r];
    }
}

extern "C" void kernel_launch(void* const* d_in, const int* in_sizes, int n_in,
                              void* d_out, int out_size, void* d_ws, size_t ws_size,
                              hipStream_t stream) {
  const float* x = (const float*)d_in[0];
  const int* mask = (const int*)d_in[1];
  const float* Wqv = (const float*)d_in[2];
  const float* rr = (const float*)d_in[3];
  const float* rw = (const float*)d_in[4];
  float* out = (float*)d_out;
  char* ws = (char*)d_ws;
  const size_t MB = 1024 * 1024;
  _Float16* xh = (_Float16*)(ws);
  _Float16* wT = (_Float16*)(ws + 8 * MB);
  _Float16* posP = (_Float16*)(ws + 12 * MB);
  _Float16* qrr = (_Float16*)(ws + 13 * MB);
  _Float16* qrwp = (_Float16*)(ws + 21 * MB);
  _Float16* v = (_Float16*)(ws + 29 * MB);
  _Float16* vT = (_Float16*)(ws + 37 * MB);

  k_cast_x<<<2048, 256, 0, stream>>>(x, xh);
  k_posP<<<128, 256, 0, stream>>>(posP);
  k_trans_w<<<512, 256, 0, stream>>>(Wqv, wT);
  k_gemm<<<512, 256, 0, stream>>>(xh, wT, rr, rw, qrr, qrwp, v);
  k_trans_v<<<1024, 256, 0, stream>>>(v, vT);
  k_attn<<<1024, 256, 0, stream>>>(xh, qrr, qrwp, vT, posP, mask, out);
}

// Round 7
// 80.074 us; speedup vs baseline: 3.8386x; 1.7468x over previous
//
#include <hip/hip_runtime.h>

// RelativeMultiHeadAttn: B=8 S=512 D_MODEL=1024 H=16 HD=64
// Round 6: k_attn stages shared [K|posP] + V^T tiles to LDS (global_load_lds,
//          XOR-swizzled source, linear dest); k_gemm writes vT directly.
//   ws layout (bytes):
//     xh   @ 0MiB  : x cast to fp16             [4096][1024]  (8 MiB)
//     wT   @ 8MiB  : Wqv transposed fp16        [2048][1024]  (4 MiB)
//     posP @ 12MiB : [sin(t f), cos(t f)] fp16  [512][64]     (64 KiB)
//     qrr  @ 13MiB : q + r_r_bias fp16          [B,H,S,64]    (8 MiB)
//     qrwp @ 21MiB : rot(q + r_w_bias) fp16     [B,H,S,64]    (8 MiB)
//     vT   @ 29MiB : v transposed fp16          [B,H,64,S]    (8 MiB)

using h4 = __attribute__((ext_vector_type(4))) _Float16;
using h8 = __attribute__((ext_vector_type(8))) _Float16;
using f32x4 = __attribute__((ext_vector_type(4))) float;

#define MFMA16(a, b, c) __builtin_amdgcn_mfma_f32_16x16x32_f16((a), (b), (c), 0, 0, 0)

#define GLOAD_LDS16(gp, lp)                                                        \
  __builtin_amdgcn_global_load_lds(                                                \
      (const __attribute__((address_space(1))) unsigned int*)(gp),                 \
      (__attribute__((address_space(3))) unsigned int*)(lp), 16, 0, 0)

// ---- cast x (fp32 -> fp16), 4,194,304 elems, 8/thread --------------------
__global__ __launch_bounds__(256) void k_cast_x(const float* __restrict__ x,
                                                _Float16* __restrict__ xh) {
  size_t idx = (size_t)blockIdx.x * 256 + threadIdx.x;
  const float* src = x + idx * 8;
  _Float16 tmp[8];
#pragma unroll
  for (int j = 0; j < 8; ++j) tmp[j] = (_Float16)src[j];
  *(h8*)(xh + idx * 8) = *(const h8*)tmp;
}

// ---- pos' table: posP[t][j] = j<32 ? sin(t f_j) : cos(t f_{j-32}) ---------
__global__ __launch_bounds__(256) void k_posP(_Float16* __restrict__ posP) {
  int idx = blockIdx.x * 256 + threadIdx.x;  // 512*64 = 32768 exactly
  int t = idx >> 6, j = idx & 63;
  int jj = j & 31;
  float f = expf((float)jj * (-9.210340371976184f / 31.0f));  // 10000^(-jj/31)
  float ang = (float)t * f;
  posP[idx] = (_Float16)((j < 32) ? sinf(ang) : cosf(ang));
}

// ---- transpose + cast Wqv [1024][2048] fp32 -> wT [2048][1024] fp16 ------
__global__ __launch_bounds__(256) void k_trans_w(const float* __restrict__ Wqv,
                                                 _Float16* __restrict__ wT) {
  __shared__ _Float16 t[64][72];
  int bk = blockIdx.x & 15, bn = blockIdx.x >> 4;  // 16 x 32 tiles of 64x64
  int k0 = bk * 64, n0 = bn * 64;
  int r = threadIdx.x >> 2, c = (threadIdx.x & 3) * 16;
  const float* src = Wqv + (size_t)(k0 + r) * 2048 + n0 + c;
#pragma unroll
  for (int j = 0; j < 16; ++j) t[r][c + j] = (_Float16)src[j];
  __syncthreads();
  _Float16 tmp[16];
#pragma unroll
  for (int j = 0; j < 16; ++j) tmp[j] = t[c + j][r];
  _Float16* dst = wT + (size_t)(n0 + r) * 1024 + k0 + c;
  *(h8*)dst = *(const h8*)tmp;
  *(h8*)(dst + 8) = *(const h8*)(tmp + 8);
}

// ---- GEMM qv = x @ Wqv, 128x128x32 LDS-staged (m97 structure) -------------
// Epilogue: heads 0-15 -> qrr + rotated qrwp ; heads 16-31 -> vT directly.
__global__ __launch_bounds__(256) void k_gemm(const _Float16* __restrict__ xh,
                                              const _Float16* __restrict__ wT,
                                              const float* __restrict__ rr,
                                              const float* __restrict__ rw,
                                              _Float16* __restrict__ qrr,
                                              _Float16* __restrict__ qrwp,
                                              _Float16* __restrict__ vT) {
  __shared__ _Float16 At[128 * 32];
  __shared__ _Float16 Bt[128 * 32];

  int bid = blockIdx.x;
  int bm = bid & 31, bn = bid >> 5;
  int tid = threadIdx.x;
  int w = tid >> 6, lane = tid & 63;
  int lr = lane & 15, lg = lane >> 4;

  const _Float16* gA = xh + (size_t)(bm * 128 + 32 * w + (lane >> 2)) * 1024 + (lane & 3) * 8;
  const _Float16* gB = wT + (size_t)(bn * 128 + 32 * w + (lane >> 2)) * 1024 + (lane & 3) * 8;
  _Float16* lA0 = &At[(32 * w) * 32];
  _Float16* lA1 = &At[(32 * w + 16) * 32];
  _Float16* lB0 = &Bt[(32 * w) * 32];
  _Float16* lB1 = &Bt[(32 * w + 16) * 32];

  int wm = w >> 1, wn = w & 1;
  const _Float16* la = &At[(wm * 64 + lr) * 32 + lg * 8];
  const _Float16* lb = &Bt[(wn * 64 + lr) * 32 + lg * 8];

  f32x4 acc[4][4] = {};

  for (int k0 = 0; k0 < 1024; k0 += 32) {
    GLOAD_LDS16(gA + k0, lA0);
    GLOAD_LDS16(gA + 16 * 1024 + k0, lA1);
    GLOAD_LDS16(gB + k0, lB0);
    GLOAD_LDS16(gB + 16 * 1024 + k0, lB1);
    __syncthreads();
    h8 af[4], bf[4];
#pragma unroll
    for (int mi = 0; mi < 4; ++mi) af[mi] = *(const h8*)(la + mi * 512);
#pragma unroll
    for (int ni = 0; ni < 4; ++ni) bf[ni] = *(const h8*)(lb + ni * 512);
#pragma unroll
    for (int mi = 0; mi < 4; ++mi)
#pragma unroll
      for (int ni = 0; ni < 4; ++ni)
        acc[mi][ni] = MFMA16(af[mi], bf[ni], acc[mi][ni]);
    __syncthreads();
  }

  int hg = bn * 2 + wn;
  int mb = bm * 128 + wm * 64;
  if (hg < 16) {
    int h = hg;
    float rrv[4], rwv[4];
#pragma unroll
    for (int ni = 0; ni < 4; ++ni) {
      rrv[ni] = rr[h * 64 + ni * 16 + lr];
      rwv[ni] = rw[h * 64 + ni * 16 + lr];
    }
    float f0 = expf((float)lr * (-9.210340371976184f / 31.0f));
    float f1 = expf((float)(16 + lr) * (-9.210340371976184f / 31.0f));
#pragma unroll
    for (int mi = 0; mi < 4; ++mi)
#pragma unroll
      for (int r = 0; r < 4; ++r) {
        int m = mb + mi * 16 + lg * 4 + r;
        int b = m >> 9, s = m & 511;
        size_t base = ((size_t)(b * 16 + h) * 512 + s) * 64;
#pragma unroll
        for (int ni = 0; ni < 4; ++ni)
          qrr[base + ni * 16 + lr] = (_Float16)(acc[mi][ni][r] + rrv[ni]);
        {
          float qs = acc[mi][0][r] + rwv[0], qc = acc[mi][2][r] + rwv[2];
          float sn, cs;
          sincosf((float)s * f0, &sn, &cs);
          qrwp[base + lr] = (_Float16)(qs * cs + qc * sn);
          qrwp[base + lr + 32] = (_Float16)(qc * cs - qs * sn);
        }
        {
          float qs = acc[mi][1][r] + rwv[1], qc = acc[mi][3][r] + rwv[3];
          float sn, cs;
          sincosf((float)s * f1, &sn, &cs);
          qrwp[base + 16 + lr] = (_Float16)(qs * cs + qc * sn);
          qrwp[base + 16 + lr + 32] = (_Float16)(qc * cs - qs * sn);
        }
      }
  } else {
    int h = hg - 16;
#pragma unroll
    for (int mi = 0; mi < 4; ++mi) {
      int m = mb + mi * 16 + lg * 4;
      int b = m >> 9, s0 = m & 511;  // constant over r (4 contiguous rows)
      size_t vtbase = (size_t)(b * 16 + h) * 64 * 512;
#pragma unroll
      for (int ni = 0; ni < 4; ++ni) {
        int d = ni * 16 + lr;
        _Float16 t4[4];
#pragma unroll
        for (int r = 0; r < 4; ++r) t4[r] = (_Float16)acc[mi][ni][r];
        *(h4*)(vT + vtbase + (size_t)d * 512 + s0) = *(const h4*)t4;
      }
    }
  }
}

// ---- flash attention: one block per (b, h, 64-row q-block) ----------------
// Decode: qb = bid>>7 -> all 8 q-blocks of one (b,h) share bid mod 8 (XCD).
// Per 128-wide KV tile, stage shared operands to LDS once per block:
//   Kp[128][128] fp16 : row t = [K(t,0:64) | posP(t,0:64)]  (16B-chunk XOR swizzle)
//   Vt[64][128]  fp16 : row d = V^T(d, t0:t0+128)           (same swizzle)
// Swizzle: LDS dest linear, global SOURCE chunk c16 ^= (row&15); reads apply
// the same XOR -> involution, conflict-free ds_read_b128 (rows are 256B).
__global__ __launch_bounds__(256, 2) void k_attn(const _Float16* __restrict__ xh,
                                                 const _Float16* __restrict__ qrr,
                                                 const _Float16* __restrict__ qrwp,
                                                 const _Float16* __restrict__ vT,
                                                 const _Float16* __restrict__ posPg,
                                                 const int* __restrict__ mask,
                                                 float* __restrict__ out) {
  __shared__ _Float16 Kp[128 * 128];    // 32 KiB
  __shared__ _Float16 Vt[64 * 128];     // 16 KiB
  __shared__ _Float16 Pl[4][16 * 136];  // per-wave P tile (stride 136 fp16)
  __shared__ float Ms[512];             // mask as float

  int bid = blockIdx.x;
  int qb = bid >> 7, h = bid & 15, b = (bid >> 4) & 7;
  int q0 = qb * 64;
  int tid = threadIdx.x;
  int w = tid >> 6, lane = tid & 63;
  int lr = lane & 15, lg = lane >> 4;

  const size_t bh = (size_t)(b * 16 + h);
  const _Float16* qrr_p = qrr + (bh * 512 + q0 + 16 * w + lr) * 64 + lg * 8;
  const _Float16* qrw_p = qrwp + (bh * 512 + q0 + 16 * w + lr) * 64 + lg * 8;
  const _Float16* kb = xh + (size_t)b * 512 * 1024 + h * 64;
  const _Float16* vTp = vT + bh * 64 * 512;
  const int* mrow = mask + b * 512;

  Ms[tid] = (float)mrow[tid];
  Ms[tid + 256] = (float)mrow[tid + 256];

  // Hoist A-fragments (same for every k-tile).
  h8 ar0 = *(const h8*)(qrr_p);
  h8 ar1 = *(const h8*)(qrr_p + 32);
  h8 aw0 = *(const h8*)(qrw_p);
  h8 aw1 = *(const h8*)(qrw_p + 32);

  float m_run[4], l_run[4];
  f32x4 O[4];  // O[df][r]
#pragma unroll
  for (int r = 0; r < 4; ++r) { m_run[r] = -1e30f; l_run[r] = 0.f; }
#pragma unroll
  for (int df = 0; df < 4; ++df) O[df] = (f32x4){0.f, 0.f, 0.f, 0.f};

  _Float16* pw = &Pl[w][0];

  for (int t0 = 0; t0 < 512; t0 += 128) {
    // ---- stage Kp: 2048 16B-chunks, wave w does chunks [w*512, w*512+512)
#pragma unroll
    for (int it = 0; it < 8; ++it) {
      int a = w * 512 + it * 64 + lane;
      int trow = a >> 4, c16 = a & 15;
      int c16s = c16 ^ (trow & 15);
      const _Float16* g = (c16s < 8)
          ? kb + (size_t)(t0 + trow) * 1024 + c16s * 8
          : posPg + (size_t)(t0 + trow) * 64 + (c16s - 8) * 8;
      GLOAD_LDS16(g, &Kp[(size_t)(w * 512 + it * 64) * 8]);
    }
    // ---- stage Vt: 1024 chunks, wave w does [w*256, w*256+256)
#pragma unroll
    for (int it = 0; it < 4; ++it) {
      int a = w * 256 + it * 64 + lane;
      int drow = a >> 4, c16 = a & 15;
      int c16s = c16 ^ (drow & 15);
      const _Float16* g = vTp + (size_t)drow * 512 + t0 + c16s * 8;
      GLOAD_LDS16(g, &Vt[(size_t)(w * 256 + it * 64) * 8]);
    }
    __syncthreads();  // drains vmcnt -> tiles (and Ms on first iter) ready

    // ---- scores s[tf][r] (row = lg*4+r, col = tf*16+lr): K=128 from LDS ---
    float s[8][4];
#pragma unroll
    for (int tf = 0; tf < 8; ++tf) {
      int row = tf * 16 + lr;  // row & 15 == lr
      const _Float16* bp = &Kp[row * 128];
      h8 b0 = *(const h8*)(bp + ((0 + lg) ^ lr) * 8);
      h8 b1 = *(const h8*)(bp + ((4 + lg) ^ lr) * 8);
      h8 b2 = *(const h8*)(bp + ((8 + lg) ^ lr) * 8);
      h8 b3 = *(const h8*)(bp + ((12 + lg) ^ lr) * 8);
      f32x4 c = {0.f, 0.f, 0.f, 0.f};
      c = MFMA16(ar0, b0, c);
      c = MFMA16(ar1, b1, c);
      c = MFMA16(aw0, b2, c);
      c = MFMA16(aw1, b3, c);
      float mm = Ms[t0 + tf * 16 + lr];
#pragma unroll
      for (int r = 0; r < 4; ++r) s[tf][r] = c[r] * mm - (1.f - mm) * 1e8f;
    }

    // ---- online softmax (reduce across the 16 lanes holding each row) -----
#pragma unroll
    for (int r = 0; r < 4; ++r) {
      float rm = s[0][r];
#pragma unroll
      for (int tf = 1; tf < 8; ++tf) rm = fmaxf(rm, s[tf][r]);
#pragma unroll
      for (int d = 1; d < 16; d <<= 1) rm = fmaxf(rm, __shfl_xor(rm, d));
      float mn = fmaxf(m_run[r], rm);
      float sc = __expf(m_run[r] - mn);
      m_run[r] = mn;
      float rs = 0.f;
#pragma unroll
      for (int tf = 0; tf < 8; ++tf) {
        float p = __expf(s[tf][r] - mn);
        _Float16 p16 = (_Float16)p;
        pw[(lg * 4 + r) * 136 + tf * 16 + lr] = p16;
        rs += (float)p16;  // accumulate rounded value for PV consistency
      }
#pragma unroll
      for (int d = 1; d < 16; d <<= 1) rs += __shfl_xor(rs, d);
      l_run[r] = l_run[r] * sc + rs;
#pragma unroll
      for (int df = 0; df < 4; ++df) O[df][r] *= sc;
    }

    // ---- PV: P (wave-private LDS) as A, V from shared LDS as B ------------
    h8 pa[4];
#pragma unroll
    for (int ks = 0; ks < 4; ++ks)
      pa[ks] = *(const h8*)(pw + lr * 136 + ks * 32 + lg * 8);
#pragma unroll
    for (int df = 0; df < 4; ++df) {
      int row = df * 16 + lr;  // row & 15 == lr
      const _Float16* vbp = &Vt[row * 128];
#pragma unroll
      for (int ks = 0; ks < 4; ++ks) {
        h8 vb = *(const h8*)(vbp + ((ks * 4 + lg) ^ lr) * 8);
        O[df] = MFMA16(pa[ks], vb, O[df]);
      }
    }
    __syncthreads();  // all LDS reads done before next tile's staging
  }

  // ---- epilogue: normalize and store
#pragma unroll
  for (int df = 0; df < 4; ++df)
#pragma unroll
    for (int r = 0; r < 4; ++r) {
      int ii = 16 * w + lg * 4 + r;
      out[((size_t)b * 512 + q0 + ii) * 1024 + h * 64 + df * 16 + lr] = O[df][r] / l_run[r];
    }
}

extern "C" void kernel_launch(void* const* d_in, const int* in_sizes, int n_in,
                              void* d_out, int out_size, void* d_ws, size_t ws_size,
                              hipStream_t stream) {
  const float* x = (const float*)d_in[0];
  const int* mask = (const int*)d_in[1];
  const float* Wqv = (const float*)d_in[2];
  const float* rr = (const float*)d_in[3];
  const float* rw = (const float*)d_in[4];
  float* out = (float*)d_out;
  char* ws = (char*)d_ws;
  const size_t MB = 1024 * 1024;
  _Float16* xh = (_Float16*)(ws);
  _Float16* wT = (_Float16*)(ws + 8 * MB);
  _Float16* posP = (_Float16*)(ws + 12 * MB);
  _Float16* qrr = (_Float16*)(ws + 13 * MB);
  _Float16* qrwp = (_Float16*)(ws + 21 * MB);
  _Float16* vT = (_Float16*)(ws + 29 * MB);

  k_cast_x<<<2048, 256, 0, stream>>>(x, xh);
  k_posP<<<128, 256, 0, stream>>>(posP);
  k_trans_w<<<512, 256, 0, stream>>>(Wqv, wT);
  k_gemm<<<512, 256, 0, stream>>>(xh, wT, rr, rw, qrr, qrwp, vT);
  k_attn<<<1024, 256, 0, stream>>>(xh, qrr, qrwp, vT, posP, mask, out);
}